// Round 2
// 550.965 us; speedup vs baseline: 1.1057x; 1.1057x over previous
//
#include <hip/hip_runtime.h>
#include <hip/hip_bf16.h>

#define S_LEN 2048
#define HID 4096
#define NH 32
#define NKV 8
#define DH 128
#define QKV_N ((NH + 2 * NKV) * DH) /* 6144 */
#define SCALE_ATT 0.08838834764831845f /* 128^-0.5 */
#define SCALE2_ATT 0.12751744f         /* SCALE_ATT * log2(e) */

typedef __bf16 bf16;
typedef __bf16 bf16x8 __attribute__((ext_vector_type(8)));
typedef __bf16 bf16x4 __attribute__((ext_vector_type(4)));
typedef float f32x4 __attribute__((ext_vector_type(4)));
typedef float f32x16 __attribute__((ext_vector_type(16)));

__device__ inline f32x4 mfma16(bf16x8 a, bf16x8 b, f32x4 c) {
    return __builtin_amdgcn_mfma_f32_16x16x32_bf16(a, b, c, 0, 0, 0);
}
__device__ inline f32x16 mfma32(bf16x8 a, bf16x8 b, f32x16 c) {
    return __builtin_amdgcn_mfma_f32_32x32x16_bf16(a, b, c, 0, 0, 0);
}

__device__ inline bf16x8 load8(const float* p) {
    const float4 a = ((const float4*)p)[0];
    const float4 b = ((const float4*)p)[1];
    bf16x8 r;
    r[0] = (bf16)a.x; r[1] = (bf16)a.y; r[2] = (bf16)a.z; r[3] = (bf16)a.w;
    r[4] = (bf16)b.x; r[5] = (bf16)b.y; r[6] = (bf16)b.z; r[7] = (bf16)b.w;
    return r;
}
__device__ inline bf16x8 load8(const bf16* p) { return *(const bf16x8*)p; }

// direct global->LDS DMA, 16 bytes/lane. LDS dest is wave-uniform base + lane*16.
__device__ inline void load_lds16(const bf16* g, bf16* lds_base) {
    __builtin_amdgcn_global_load_lds(
        (const __attribute__((address_space(1))) void*)g,
        (__attribute__((address_space(3))) void*)lds_base, 16, 0, 0);
}

// pack 2 f32 -> 1 u32 holding 2 bf16 (let the compiler pick cvt_pk; m240)
__device__ inline unsigned pack2_bf16(float lo, float hi) {
    union { bf16 h[2]; unsigned u; } r;
    r.h[0] = (bf16)lo;
    r.h[1] = (bf16)hi;
    return r.u;
}

// fp32 -> bf16 bulk convert (8 elts/thread)
__global__ __launch_bounds__(256) void cvt_kernel(const float* __restrict__ src,
                                                  bf16* __restrict__ dst, int n8) {
    int i = blockIdx.x * 256 + threadIdx.x;
    if (i >= n8) return;
    *(bf16x8*)&dst[(size_t)i * 8] = load8(&src[(size_t)i * 8]);
}

// ---------------- swizzled bf16 GEMM (global_load_lds path) ----------------
template <typename OutT>
__global__ __launch_bounds__(256) void gemm_bt_swz(const bf16* __restrict__ A,
                                                   const bf16* __restrict__ B,
                                                   OutT* __restrict__ C,
                                                   int K, int lda, int ldc) {
    const int tid = threadIdx.x;
    const int lane = tid & 63;
    const int w = tid >> 6;
    const int m0 = blockIdx.y * 128;
    const int n0 = blockIdx.x * 128;
    const int wm = (w >> 1) * 64;
    const int wn = (w & 1) * 64;
    const int ln = lane & 15;
    const int qo = lane >> 4;

    __shared__ bf16 As[128 * 64];
    __shared__ bf16 Bs[128 * 64];

    const int rseg = lane >> 3;
    const int gc = (lane & 7) ^ (rseg & 7);

    f32x4 acc[4][4];
#pragma unroll
    for (int mi = 0; mi < 4; ++mi)
#pragma unroll
        for (int ni = 0; ni < 4; ++ni) acc[mi][ni] = f32x4{0.f, 0.f, 0.f, 0.f};

    for (int k0 = 0; k0 < K; k0 += 64) {
#pragma unroll
        for (int j = 0; j < 4; ++j) {
            const int seg = w * 4 + j;
            const int r = seg * 8 + rseg;
            load_lds16(&A[(size_t)(m0 + r) * lda + k0 + gc * 8], &As[seg * 512]);
            load_lds16(&B[(size_t)(n0 + r) * K + k0 + gc * 8], &Bs[seg * 512]);
        }
        __syncthreads();
#pragma unroll
        for (int kk = 0; kk < 2; ++kk) {
            bf16x8 af[4], bfr[4];
#pragma unroll
            for (int mi = 0; mi < 4; ++mi) {
                const int m = wm + mi * 16 + ln;
                const int sc = (kk * 4 + qo) ^ (ln & 7);
                af[mi] = *(const bf16x8*)&As[m * 64 + sc * 8];
            }
#pragma unroll
            for (int ni = 0; ni < 4; ++ni) {
                const int n = wn + ni * 16 + ln;
                const int sc = (kk * 4 + qo) ^ (ln & 7);
                bfr[ni] = *(const bf16x8*)&Bs[n * 64 + sc * 8];
            }
#pragma unroll
            for (int mi = 0; mi < 4; ++mi)
#pragma unroll
                for (int ni = 0; ni < 4; ++ni)
                    acc[mi][ni] = mfma16(af[mi], bfr[ni], acc[mi][ni]);
        }
        __syncthreads();
    }
#pragma unroll
    for (int mi = 0; mi < 4; ++mi)
#pragma unroll
        for (int ni = 0; ni < 4; ++ni)
#pragma unroll
            for (int r = 0; r < 4; ++r) {
                int row = m0 + wm + mi * 16 + qo * 4 + r;
                int col = n0 + wn + ni * 16 + ln;
                C[(size_t)row * ldc + col] = (OutT)acc[mi][ni][r];
            }
}

// ---------------- fallback fp32-staging GEMM ----------------
template <typename AT, typename OutT>
__global__ __launch_bounds__(256) void gemm_bt(const AT* __restrict__ A,
                                               const float* __restrict__ B,
                                               OutT* __restrict__ C,
                                               int K, int lda, int ldc) {
    const int tid = threadIdx.x;
    const int lane = tid & 63;
    const int w = tid >> 6;
    const int m0 = blockIdx.y * 128;
    const int n0 = blockIdx.x * 128;
    const int wm = (w >> 1) * 64;
    const int wn = (w & 1) * 64;
    const int ln = lane & 15;
    const int qo = lane >> 4;

    __shared__ bf16 As[128 * 72];
    __shared__ bf16 Bs[128 * 72];

    f32x4 acc[4][4];
#pragma unroll
    for (int mi = 0; mi < 4; ++mi)
#pragma unroll
        for (int ni = 0; ni < 4; ++ni) acc[mi][ni] = f32x4{0.f, 0.f, 0.f, 0.f};

    for (int k0 = 0; k0 < K; k0 += 64) {
#pragma unroll
        for (int i = 0; i < 4; ++i) {
            int v = tid + i * 256;
            int row = v >> 3;
            int col = (v & 7) * 8;
            *(bf16x8*)&As[row * 72 + col] = load8(&A[(size_t)(m0 + row) * lda + k0 + col]);
            *(bf16x8*)&Bs[row * 72 + col] = load8(&B[(size_t)(n0 + row) * K + k0 + col]);
        }
        __syncthreads();
#pragma unroll
        for (int kk = 0; kk < 64; kk += 32) {
            bf16x8 af[4], bfr[4];
#pragma unroll
            for (int mi = 0; mi < 4; ++mi)
                af[mi] = *(const bf16x8*)&As[(wm + mi * 16 + ln) * 72 + kk + qo * 8];
#pragma unroll
            for (int ni = 0; ni < 4; ++ni)
                bfr[ni] = *(const bf16x8*)&Bs[(wn + ni * 16 + ln) * 72 + kk + qo * 8];
#pragma unroll
            for (int mi = 0; mi < 4; ++mi)
#pragma unroll
                for (int ni = 0; ni < 4; ++ni)
                    acc[mi][ni] = mfma16(af[mi], bfr[ni], acc[mi][ni]);
        }
        __syncthreads();
    }
#pragma unroll
    for (int mi = 0; mi < 4; ++mi)
#pragma unroll
        for (int ni = 0; ni < 4; ++ni)
#pragma unroll
            for (int r = 0; r < 4; ++r) {
                int row = m0 + wm + mi * 16 + qo * 4 + r;
                int col = n0 + wn + ni * 16 + ln;
                C[(size_t)row * ldc + col] = (OutT)acc[mi][ni][r];
            }
}

// RoPE in-place on bf16 qkv buffer
__global__ __launch_bounds__(256) void rope_kernel(bf16* __restrict__ qkv,
                                                   const int* __restrict__ positions) {
    int idx = blockIdx.x * 256 + threadIdx.x;
    const int total = S_LEN * (NH + NKV) * 64;
    if (idx >= total) return;
    int d = idx & 63;
    int t = idx >> 6;
    int head = t % (NH + NKV);
    int s = t / (NH + NKV);
    size_t base = (size_t)s * QKV_N + (head < NH ? head * DH : NH * DH + (head - NH) * DH);
    float x1 = (float)qkv[base + d];
    float x2 = (float)qkv[base + d + 64];
    float pos = (float)positions[s];
    float inv = expf(-0.21586735246819178f * (float)d);
    float ang = pos * inv;
    float c = cosf(ang);
    float sn = sinf(ang);
    qkv[base + d] = (bf16)(x1 * c - x2 * sn);
    qkv[base + d + 64] = (bf16)(x2 * c + x1 * sn);
}

// Pre-transpose V into vt_g[kvh][d][s]
__global__ __launch_bounds__(256) void vtrans_kernel(const bf16* __restrict__ qkv,
                                                     bf16* __restrict__ vt_g) {
    const int tid = threadIdx.x;
    const int s0 = blockIdx.x * 64;
    const int kvh = blockIdx.y;
    __shared__ bf16 Ls[64 * 136];
#pragma unroll
    for (int i = 0; i < 4; ++i) {
        int v = tid + i * 256;
        int row = v >> 4;
        int col = (v & 15) * 8;
        *(bf16x8*)&Ls[row * 136 + col] =
            *(const bf16x8*)&qkv[(size_t)(s0 + row) * QKV_N + (NH + NKV) * DH + kvh * DH + col];
    }
    __syncthreads();
#pragma unroll
    for (int i = 0; i < 4; ++i) {
        int u = tid + i * 256;
        int d = u >> 3;
        int sg = (u & 7) * 8;
        bf16x8 r;
#pragma unroll
        for (int j = 0; j < 8; ++j) r[j] = Ls[(sg + j) * 136 + d];
        *(bf16x8*)&vt_g[((size_t)kvh * DH + d) * S_LEN + s0 + sg] = r;
    }
}

// ---------------------------------------------------------------------------
// Flash attention, m214-style: 4 warps x 32 q-rows (128 q/block), KVBLK=64,
// 32x32x16 MFMA, swapped QK^T (lane owns one q's full P row), in-register
// softmax (+1 shfl), P->PV via cross-half exchange, PV as O^T = Vt @ P^T
// (rescale lane-local). K/Vt: global_load_lds DMA into XOR-chunk-swizzled
// LDS, double buffered, ONE barrier per KV tile (next-tile DMA in flight
// under compute). O -> Q slot of qkv in-place.
// ---------------------------------------------------------------------------
__global__ __launch_bounds__(256) void attn_kernel(bf16* __restrict__ qkv,
                                                   const bf16* __restrict__ vt_g) {
    const int tid = threadIdx.x;
    const int lane = tid & 63;
    const int w = tid >> 6;
    const int ln = lane & 31;
    const int hi = lane >> 5;
    const int hq = blockIdx.x;
    const int qtile = (int)gridDim.y - 1 - (int)blockIdx.y; // heavy first
    const int kvh = hq >> 2;
    const int q0 = qtile * 128;
    const int qrow = q0 + w * 32 + ln;

    // K: [2][64 rows][128 d], chunk c at slot c^(row&7) (chunk = 8 bf16 = 16B)
    // Vt: [2][128 d][64 s], chunk c at slot c^(d&7)
    __shared__ __align__(128) bf16 Ks[2][64 * 128];  // 2 x 16 KB
    __shared__ __align__(128) bf16 Vt[2][128 * 64];  // 2 x 16 KB

    // Q fragments (B-operand): lane = col q, elems Q[q][s*16 + hi*8 + j]
    bf16x8 qf[8];
    {
        const bf16* qptr = qkv + (size_t)qrow * QKV_N + hq * DH + hi * 8;
#pragma unroll
        for (int s = 0; s < 8; ++s) qf[s] = *(const bf16x8*)(qptr + s * 16);
    }

    const bf16* ksrc = qkv + NH * DH + kvh * DH;
    const bf16* vsrc = vt_g + (size_t)kvh * DH * S_LEN;
    const int kcK = lane & 15;   // K chunk slot (16/row)
    const int krs = lane >> 4;   // K row within 4-row group
    const int kcV = lane & 7;    // V chunk slot (8/row)
    const int vrs = lane >> 3;   // V row within 8-row group

    auto stage = [&](int buf, int kt) {
        const int k0s = kt * 64;
#pragma unroll
        for (int j = 0; j < 4; ++j) {
            int r = w * 16 + j * 4 + krs;
            load_lds16(ksrc + (size_t)(k0s + r) * QKV_N + ((kcK ^ (r & 7)) * 8),
                       &Ks[buf][(w * 16 + j * 4) * 128]);
        }
#pragma unroll
        for (int j = 0; j < 4; ++j) {
            int d = w * 32 + j * 8 + vrs;
            load_lds16(vsrc + (size_t)d * S_LEN + k0s + ((kcV ^ (d & 7)) * 8),
                       &Vt[buf][(w * 32 + j * 8) * 64]);
        }
    };

    f32x16 acc[4]; // O^T: acc[dt], row d = dt*32 + crow(r,hi), col q = ln
#pragma unroll
    for (int t = 0; t < 4; ++t)
#pragma unroll
        for (int r = 0; r < 16; ++r) acc[t][r] = 0.f;
    float m2 = -1e30f, l = 0.f; // running max (log2 domain) and denom

    const int kt_last = (q0 + 127) >> 6;
    int buf = 0;
    stage(0, 0);
    __syncthreads();

    for (int kt = 0; kt <= kt_last; ++kt) {
        if (kt < kt_last) stage(buf ^ 1, kt + 1); // DMA in flight under compute
        const int k0 = kt * 64;
        if (k0 <= q0 + w * 32 + 31) { // warp-uniform: skip fully-masked tiles
            // ---- QK^T swapped: ST[key][q], q = ln ----
            f32x16 st[2];
#pragma unroll
            for (int t = 0; t < 2; ++t)
#pragma unroll
                for (int r = 0; r < 16; ++r) st[t][r] = 0.f;
            const bf16* Kb = &Ks[buf][0];
            __builtin_amdgcn_s_setprio(1);
#pragma unroll
            for (int t = 0; t < 2; ++t) {
                const int key = t * 32 + ln;
#pragma unroll
                for (int s = 0; s < 8; ++s) {
                    bf16x8 kf =
                        *(const bf16x8*)&Kb[key * 128 + (((2 * s + hi) ^ (key & 7)) * 8)];
                    st[t] = mfma32(kf, qf[s], st[t]);
                }
            }
            __builtin_amdgcn_s_setprio(0);
            // ---- softmax (in-register, log2 domain) ----
            const bool needMask = (k0 + 63 > q0 + w * 32);
            float tmax = -1e30f;
#pragma unroll
            for (int t = 0; t < 2; ++t)
#pragma unroll
                for (int r = 0; r < 16; ++r) {
                    int kcol = k0 + t * 32 + (r & 3) + 8 * (r >> 2) + 4 * hi;
                    float v = st[t][r] * SCALE2_ATT;
                    if (needMask && kcol > qrow) v = -1e30f;
                    st[t][r] = v;
                    tmax = fmaxf(tmax, v);
                }
            tmax = fmaxf(tmax, __shfl_xor(tmax, 32, 64));
            float mnew = fmaxf(m2, tmax);
            float alpha = exp2f(m2 - mnew);
            float rs = 0.f;
#pragma unroll
            for (int t = 0; t < 2; ++t)
#pragma unroll
                for (int r = 0; r < 16; ++r) {
                    float e = exp2f(st[t][r] - mnew);
                    st[t][r] = e;
                    rs += e;
                }
            rs += __shfl_xor(rs, 32, 64);
            l = l * alpha + rs;
            m2 = mnew;
#pragma unroll
            for (int t = 0; t < 4; ++t)
#pragma unroll
                for (int r = 0; r < 16; ++r) acc[t][r] *= alpha;
            // ---- P -> bf16 B-fragments (cross-half exchange via shfl_xor 32) ----
            // word i holds keys 32*(i>>3) + 8*((i>>1)&3) + 4*hi + 2*(i&1) + {0,1}
            unsigned cw[16];
#pragma unroll
            for (int i = 0; i < 16; ++i)
                cw[i] = pack2_bf16(st[i >> 3][2 * (i & 7)], st[i >> 3][2 * (i & 7) + 1]);
            bf16x8 pa[4]; // pa[ks]: keys ks*16 + hi*8 + {0..7}, col q = ln
#pragma unroll
            for (int ks = 0; ks < 4; ++ks) {
                const int base = (ks >> 1) * 8 + (ks & 1) * 4;
                union { unsigned u[4]; bf16x8 v; } pk;
#pragma unroll
                for (int e = 0; e < 2; ++e) {
                    unsigned A = cw[base + e];
                    unsigned B = cw[base + 2 + e];
                    // verified-by-derivation cross-half exchange:
                    // pk.u[e]   = [hi0: own A        | hi1: partner-hi0's B]
                    // pk.u[e+2] = [hi0: partner-hi1's A | hi1: own B]
                    unsigned tA = (unsigned)__shfl_xor((int)A, 32, 64);
                    unsigned tB = (unsigned)__shfl_xor((int)B, 32, 64);
                    pk.u[e] = hi ? tB : A;
                    pk.u[e + 2] = hi ? B : tA;
                }
                pa[ks] = pk.v;
            }
            // ---- PV: O^T += Vt @ P^T ----
            const bf16* Vb = &Vt[buf][0];
            __builtin_amdgcn_s_setprio(1);
#pragma unroll
            for (int dt = 0; dt < 4; ++dt) {
                const int d = dt * 32 + ln;
#pragma unroll
                for (int ks = 0; ks < 4; ++ks) {
                    bf16x8 vf =
                        *(const bf16x8*)&Vb[d * 64 + (((2 * ks + hi) ^ (d & 7)) * 8)];
                    acc[dt] = mfma32(vf, pa[ks], acc[dt]);
                }
            }
            __builtin_amdgcn_s_setprio(0);
        }
        __syncthreads(); // staged buf^1 ready; all reads of buf done
        buf ^= 1;
    }

    // ---- epilogue: O^T -> qkv Q slot (lane-local l) ----
    const float invl = 1.f / l;
    bf16* outp = qkv + (size_t)qrow * QKV_N + hq * DH;
#pragma unroll
    for (int dt = 0; dt < 4; ++dt)
#pragma unroll
        for (int rq = 0; rq < 4; ++rq) {
            bf16x4 o;
#pragma unroll
            for (int i = 0; i < 4; ++i) o[i] = (bf16)(acc[dt][rq * 4 + i] * invl);
            *(bf16x4*)(outp + dt * 32 + rq * 8 + hi * 4) = o;
        }
}

extern "C" void kernel_launch(void* const* d_in, const int* in_sizes, int n_in,
                              void* d_out, int out_size, void* d_ws, size_t ws_size,
                              hipStream_t stream) {
    const int* positions = (const int*)d_in[0];
    const float* hidden = (const float*)d_in[1];
    const float* w_qkv = (const float*)d_in[2];
    const float* w_o = (const float*)d_in[3];
    float* out = (float*)d_out;

    const size_t n_qkv = (size_t)S_LEN * QKV_N;
    const size_t n_vt = (size_t)NKV * DH * S_LEN;
    const size_t n_hid = (size_t)S_LEN * HID;
    const size_t n_wqkv = (size_t)QKV_N * HID;
    const size_t n_wo = (size_t)HID * HID;

    const size_t need_min = (n_qkv + n_vt) * sizeof(bf16);
    const size_t need_full = (n_qkv + n_vt + n_hid + n_wqkv + n_wo) * sizeof(bf16);
    if (ws_size < need_min) return;

    bf16* qkv = (bf16*)d_ws;
    bf16* vt_g = qkv + n_qkv;
    bf16* hid_b = vt_g + n_vt;
    bf16* wqkv_b = hid_b + n_hid;
    bf16* wo_b = wqkv_b + n_wqkv;
    const bool full = ws_size >= need_full;

    if (full) {
        cvt_kernel<<<(int)(n_hid / 8 + 255) / 256, 256, 0, stream>>>(hidden, hid_b, (int)(n_hid / 8));
        cvt_kernel<<<(int)(n_wqkv / 8 + 255) / 256, 256, 0, stream>>>(w_qkv, wqkv_b, (int)(n_wqkv / 8));
        cvt_kernel<<<(int)(n_wo / 8 + 255) / 256, 256, 0, stream>>>(w_o, wo_b, (int)(n_wo / 8));
        gemm_bt_swz<<<dim3(QKV_N / 128, S_LEN / 128), 256, 0, stream>>>(hid_b, wqkv_b, qkv, HID, HID, QKV_N);
    } else {
        gemm_bt<<<dim3(QKV_N / 128, S_LEN / 128), 256, 0, stream>>>(hidden, w_qkv, qkv, HID, HID, QKV_N);
    }
    const int total = S_LEN * (NH + NKV) * 64;
    rope_kernel<<<(total + 255) / 256, 256, 0, stream>>>(qkv, positions);
    vtrans_kernel<<<dim3(S_LEN / 64, NKV), 256, 0, stream>>>(qkv, vt_g);
    attn_kernel<<<dim3(NH, S_LEN / 128), 256, 0, stream>>>(qkv, vt_g);
    if (full) {
        gemm_bt_swz<<<dim3(HID / 128, S_LEN / 128), 256, 0, stream>>>(qkv, wo_b, out, HID, QKV_N, HID);
    } else {
        gemm_bt<<<dim3(HID / 128, S_LEN / 128), 256, 0, stream>>>(qkv, w_o, out, HID, QKV_N, HID);
    }
}